// Round 2
// baseline (157.394 us; speedup 1.0000x reference)
//
#include <hip/hip_runtime.h>

#define BS 32
#define NA 512
#define ID 128
#define NH 8
#define HD 64
#define NHD 512   // NH*HD
#define NEG 0.2f
#define NC 32     // scalar chunk count (G=16) for zps/znp
#define CH 16
#define NW 16     // waves per block (1024 threads)
#define CHK 16    // GEMM K-chunk

// Fully fused GAT kernel: one block per (b,h), 1024 threads = 16 waves.
// Phase 0: GEMM hp = h@W_slice via wave-uniform s_load rows (k1's trick),
//          results deposited straight into LDS V[512][64] (128 KiB).
// Phase 1: s,t row-dots from LDS (rotated column index -> conflict-free).
// Phase 2: dual hybrid bitonic sort (t asc, s asc) on threads < 512.
// Phase 3: per-wave weighted seeds + cross-wave scans (in-place) + scalar
//          denominator tables zps/znp.
// Phase 4: per-s-rank js (binary search) + E[] interval table.
// Phase 5: single ascending sweep per wave; emission interval [E[j],E[j-1])
//          per position; A,B,1/den recomputed inline per emitted row.
// Global traffic: read h 8MB (once per XCD via swizzle) + W + write out 33.5MB.
// No workspace, no hp round-trip, no second kernel.
__global__ __launch_bounds__(1024) void gat_fused(
    const float* __restrict__ h, const float* __restrict__ W,
    const float* __restrict__ att, float* __restrict__ out) {
  __shared__ float V[NA * HD];                       // 131072 B
  __shared__ float tv[NA]; __shared__ float sv[NA];  // sorted t / s values
  __shared__ unsigned short tpm[NA];                 // t-order -> orig row
  __shared__ unsigned short spm[NA];                 // s-rank  -> orig row
  __shared__ float wp[NA]; __shared__ float wn[NA];
  __shared__ float sufPc[(NW + 1) * 64]; __shared__ float preNc[(NW + 1) * 64];
  __shared__ float zps[NA + 1]; __shared__ float znp[NA + 1];
  __shared__ float szP[NC]; __shared__ float szN[NC];
  __shared__ float sufZ[NC + 1]; __shared__ float preZ[NC + 1];
  __shared__ unsigned short jsr[NA]; __shared__ unsigned short Earr[NA];
  __shared__ float asrc[HD]; __shared__ float adst[HD];

  // XCD-aware swizzle: dispatch round-robins blockIdx%8 across XCDs; give
  // each XCD 4 consecutive b values (all 8 heads of a b share one L2).
  int i = blockIdx.x;
  int xcd = i & 7, slot = i >> 3;
  int b = xcd * 4 + (slot >> 3);
  int head = slot & 7;
  int bh = b * NH + head;
  int t = threadIdx.x;
  int lane = t & 63;
  int w = t >> 6;
  int wu = __builtin_amdgcn_readfirstlane(w);

  // ---- Phase 0: GEMM. Wave wu owns natural rows [32*wu, 32*wu+32). ----
  {
    float acc[32];
    #pragma unroll
    for (int rc = 0; rc < 32; ++rc) acc[rc] = 0.f;
    const float* wcol = W + head * HD + lane;            // per-lane column
    const float* hb = h + ((size_t)b * NA + wu * 32) * ID;  // wave-uniform
    #pragma unroll 1
    for (int kc = 0; kc < ID; kc += CHK) {
      float wch[CHK];
      #pragma unroll
      for (int kk = 0; kk < CHK; ++kk)
        wch[kk] = wcol[(size_t)(kc + kk) * NHD];
      #pragma unroll
      for (int rc = 0; rc < 32; ++rc) {
        const float* ar = hb + rc * ID + kc;             // uniform -> s_load
        float t0 = 0.f, t1 = 0.f, t2 = 0.f, t3 = 0.f;
        #pragma unroll
        for (int kk = 0; kk < CHK; kk += 4) {
          t0 += ar[kk + 0] * wch[kk + 0];
          t1 += ar[kk + 1] * wch[kk + 1];
          t2 += ar[kk + 2] * wch[kk + 2];
          t3 += ar[kk + 3] * wch[kk + 3];
        }
        acc[rc] += (t0 + t1) + (t2 + t3);
      }
    }
    #pragma unroll
    for (int rc = 0; rc < 32; ++rc)
      V[(wu * 32 + rc) * HD + lane] = acc[rc];
  }
  if (t < HD)            asrc[t]      = att[head * 128 + t];
  else if (t < 2 * HD)   adst[t - HD] = att[head * 128 + t];
  __syncthreads();

  // ---- Phase 1: s,t row-dots from LDS (rotated column: conflict-free) ----
  float vt = 0.f, vs = 0.f; int it = t, is_ = t;
  if (t < NA) {
    float s0 = 0.f, s1 = 0.f, t0 = 0.f, t1 = 0.f;
    #pragma unroll
    for (int j = 0; j < HD; j += 2) {
      int c0 = (j + t) & 63, c1 = (j + 1 + t) & 63;
      float v0 = V[t * HD + c0], v1 = V[t * HD + c1];
      s0 += v0 * asrc[c0]; s1 += v1 * asrc[c1];
      t0 += v0 * adst[c0]; t1 += v1 * adst[c1];
    }
    vs = s0 + s1; vt = t0 + t1;
  }

  // ---- Phase 2: dual hybrid bitonic sort (threads < NA active) ----
  for (int size = 2; size <= NA; size <<= 1) {
    bool dirAsc = ((t & size) == 0);
    for (int stride = size >> 1; stride > 0; stride >>= 1) {
      if (stride >= 64) {
        if (t < NA) {
          tv[t] = vt; tpm[t] = (unsigned short)it;
          sv[t] = vs; spm[t] = (unsigned short)is_;
        }
        __syncthreads();
        if (t < NA) {
          float pt = tv[t ^ stride]; int pit = tpm[t ^ stride];
          float ps = sv[t ^ stride]; int pis = spm[t ^ stride];
          bool mn = (((t & stride) == 0) == dirAsc);
          if (mn ? (pt < vt) : (pt > vt)) { vt = pt; it = pit; }
          if (mn ? (ps < vs) : (ps > vs)) { vs = ps; is_ = pis; }
        }
        __syncthreads();
      } else if (t < NA) {
        float pt = __shfl_xor(vt, stride, 64); int pit = __shfl_xor(it, stride, 64);
        float ps = __shfl_xor(vs, stride, 64); int pis = __shfl_xor(is_, stride, 64);
        bool mn = (((t & stride) == 0) == dirAsc);
        if (mn ? (pt < vt) : (pt > vt)) { vt = pt; it = pit; }
        if (mn ? (ps < vs) : (ps > vs)) { vs = ps; is_ = pis; }
      }
    }
  }
  if (t < NA) {
    tv[t] = vt; tpm[t] = (unsigned short)it;
    sv[t] = vs; spm[t] = (unsigned short)is_;
  }
  __syncthreads();

  float cmax = fmaxf(tv[NA - 1], 0.f);
  float amax = fmaxf(sv[NA - 1], 0.f);
  if (t < NA) {
    wp[t] = __expf(vt - cmax);
    wn[t] = __expf(NEG * vt - cmax);
  }
  __syncthreads();

  // ---- Phase 3a: per-wave weighted seeds (wave w: sorted rows 32w..+31) ----
  {
    float aP = 0.f, aN = 0.f;
    #pragma unroll
    for (int jj = 0; jj < 32; ++jj) {
      int j = (w << 5) + jj;
      float vv = V[(int)tpm[j] * HD + lane];
      aP += wp[j] * vv;
      aN += wn[j] * vv;
    }
    sufPc[w * 64 + lane] = aP;   // raw; converted in place below
    preNc[w * 64 + lane] = aN;
  }
  __syncthreads();

  // ---- Phase 3b: in-place cross-wave scans + scalar chunk sums ----
  if (t < 64) {
    float run = 0.f;
    sufPc[NW * 64 + t] = 0.f;
    for (int ww = NW - 1; ww >= 0; --ww) {
      run += sufPc[ww * 64 + t];
      sufPc[ww * 64 + t] = run;
    }
  } else if (t < 128) {
    int d = t - 64; float run = 0.f;
    for (int ww = 0; ww < NW; ++ww) {
      float raw = preNc[ww * 64 + d];
      preNc[ww * 64 + d] = run;
      run += raw;
    }
    preNc[NW * 64 + d] = run;
  } else if (t < 160) {
    int c = t - 128; float a = 0.f;
    for (int j = c * CH; j < c * CH + CH; ++j) a += wp[j];
    szP[c] = a;
  } else if (t < 192) {
    int c = t - 160; float a = 0.f;
    for (int j = c * CH; j < c * CH + CH; ++j) a += wn[j];
    szN[c] = a;
  }
  __syncthreads();

  if (t == 0) {
    float run = 0.f; sufZ[NC] = 0.f;
    for (int cc = NC - 1; cc >= 0; --cc) { run += szP[cc]; sufZ[cc] = run; }
  } else if (t == 1) {
    float run = 0.f;
    for (int cc = 0; cc <= NC; ++cc) { preZ[cc] = run; if (cc < NC) run += szN[cc]; }
  }
  __syncthreads();

  // ---- Phase 3c: full-resolution scalar denominator tables; Phase 4a: js ----
  if (t < NA) {
    int ch = t >> 4;
    float a = 0.f;
    for (int k = t; k < ch * CH + CH; ++k) a += wp[k];
    zps[t] = a + sufZ[ch + 1];
    float b2 = 0.f;
    for (int k = ch * CH; k < t; ++k) b2 += wn[k];
    znp[t] = preZ[ch] + b2;
    if (t == 0) { zps[NA] = 0.f; znp[NA] = preZ[NC]; }
    // js for s-rank t (vs held in reg): first sorted-t position with tv >= -vs
    float key = -vs;
    int lo = 0, hi = NA;
    while (lo < hi) { int mid = (lo + hi) >> 1; if (tv[mid] < key) lo = mid + 1; else hi = mid; }
    jsr[t] = (unsigned short)lo;
  }
  __syncthreads();

  // ---- Phase 4b: E[j] = first rank with js <= j (jsr is non-increasing) ----
  if (t < NA) {
    int lo = 0, hi = NA;
    while (lo < hi) { int mid = (lo + hi) >> 1; if ((int)jsr[mid] > t) lo = mid + 1; else hi = mid; }
    Earr[t] = (unsigned short)lo;
  }
  __syncthreads();

  // ---- Phase 5: ascending sweep with inline emission ----
  {
    float sufPv   = sufPc[w * 64 + lane];   // suffix incl. this wave's rows
    float preSeedN = preNc[w * 64 + lane];  // exact prefix before this wave
    float runN = 0.f;
    size_t obase = (size_t)bh * NA * HD + lane;
    int eprev = (w == 0) ? NA : (int)Earr[(w << 5) - 1];
    #pragma unroll 1
    for (int jj = 0; jj < 32; ++jj) {
      int j = (w << 5) + jj;
      int ecur = (int)Earr[j];
      float preNv = preSeedN + runN;
      for (int r = ecur; r < eprev; ++r) {   // ranks with js == j
        float s = sv[r];
        float A = __expf(s - amax);
        float B = __expf(NEG * s - amax);
        float inv = 1.f / (A * zps[j] + B * znp[j]);
        float x = (A * sufPv + B * preNv) * inv;
        int orow = (int)spm[r];
        out[obase + (size_t)orow * HD] = x > 0.f ? x : __expf(x) - 1.f;
      }
      float vv = V[(int)tpm[j] * HD + lane];
      sufPv -= wp[j] * vv;
      runN  += wn[j] * vv;
      eprev = ecur;
    }
    if (w == NW - 1) {                       // group js == NA: ranks [0, E[NA-1])
      float preNv = preSeedN + runN;         // total N prefix
      for (int r = 0; r < eprev; ++r) {
        float s = sv[r];
        float A = __expf(s - amax);
        float B = __expf(NEG * s - amax);
        float inv = 1.f / (A * zps[NA] + B * znp[NA]);  // zps[NA]==0
        float x = (B * preNv) * inv;
        int orow = (int)spm[r];
        out[obase + (size_t)orow * HD] = x > 0.f ? x : __expf(x) - 1.f;
      }
    }
  }
}

extern "C" void kernel_launch(void* const* d_in, const int* in_sizes, int n_in,
                              void* d_out, int out_size, void* d_ws, size_t ws_size,
                              hipStream_t stream) {
  const float* h   = (const float*)d_in[0];
  const float* W   = (const float*)d_in[1];
  const float* att = (const float*)d_in[2];
  float* out = (float*)d_out;
  (void)d_ws; (void)ws_size;

  gat_fused<<<dim3(BS * NH), dim3(1024), 0, stream>>>(h, W, att, out);
}

// Round 3
// 134.879 us; speedup vs baseline: 1.1669x; 1.1669x over previous
//
#include <hip/hip_runtime.h>

#define BS 32
#define NA 512
#define ID 128
#define NH 8
#define HD 64
#define NHD 512   // NH*HD
#define NEG 0.2f
#define NC 32     // scalar chunk count (G=16) for zps/znp
#define CH 16
#define NW 8      // waves per k2 block (512 threads)

// K1: h_prime = h @ W (fp32), written into the OUTPUT buffer (no workspace ->
// the harness's 256MiB d_ws poison-fill, ~48us/iter, is avoided). Block = 16
// rows x 512 cols, 4 waves: wave w has rows (w>>1)*8..+7 (WAVE-UNIFORM -> A
// via s_load) and cols (w&1)*256 + 4*lane. s/t tail removed (k2 recomputes).
__global__ __launch_bounds__(256) void k1_gemm(
    const float* __restrict__ h, const float* __restrict__ W,
    float* __restrict__ hp) {
  int blk = blockIdx.x;
  int b = blk >> 5;
  int n0 = (blk & 31) * 16;
  int t = threadIdx.x;
  int lane = t & 63, w = t >> 6;
  int r0 = __builtin_amdgcn_readfirstlane((w >> 1) * 8);   // 0 or 8
  int chalf = __builtin_amdgcn_readfirstlane(w & 1);
  int col = chalf * 256 + lane * 4;
  int head = col >> 6;
  int d0 = col & 63;
  const float* arow = h + ((size_t)b * NA + n0 + r0) * ID;  // uniform base
  const float* wptr = W + col;

  float4 a0c = {0,0,0,0}, a1c = {0,0,0,0}, a2c = {0,0,0,0}, a3c = {0,0,0,0};
  float4 a4c = {0,0,0,0}, a5c = {0,0,0,0}, a6c = {0,0,0,0}, a7c = {0,0,0,0};

#define K1_ROW(I, C, KK)                                                      \
  { float a_ = arow[(I) * ID + kc + (KK)];                                    \
    C.x += a_ * wv.x; C.y += a_ * wv.y; C.z += a_ * wv.z; C.w += a_ * wv.w; }
  #pragma unroll 1
  for (int kc = 0; kc < ID; kc += 8) {
    #pragma unroll
    for (int kk = 0; kk < 8; ++kk) {
      float4 wv = *(const float4*)(wptr + (size_t)(kc + kk) * NHD);
      K1_ROW(0, a0c, kk) K1_ROW(1, a1c, kk) K1_ROW(2, a2c, kk)
      K1_ROW(3, a3c, kk) K1_ROW(4, a4c, kk) K1_ROW(5, a5c, kk)
      K1_ROW(6, a6c, kk) K1_ROW(7, a7c, kk)
    }
  }
#undef K1_ROW
  size_t off = ((((size_t)b * NH + head) * NA) + (n0 + r0)) * HD + d0;
  *(float4*)(hp + off) = a0c; off += HD;
  *(float4*)(hp + off) = a1c; off += HD;
  *(float4*)(hp + off) = a2c; off += HD;
  *(float4*)(hp + off) = a3c; off += HD;
  *(float4*)(hp + off) = a4c; off += HD;
  *(float4*)(hp + off) = a5c; off += HD;
  *(float4*)(hp + off) = a6c; off += HD;
  *(float4*)(hp + off) = a7c;
}

// K2 (in-place): per (b,h) block of 512 threads. io holds hp on entry, final
// output on exit. All io reads (s/t dots, vreg fills) complete before the
// barrier preceding emission writes; blocks touch disjoint bh slices.
//  - s,t row-dots recomputed from io (L3-hot, ~2us).
//  - dual hybrid bitonic sort (t asc, s asc) with orig indices.
//  - wave w owns sorted-t rows [64w,64w+64): V rows ONCE into vreg[64]
//    (fully-unrolled, static indices), wave-local weighted sums for seeds.
//  - js monotone non-increasing over s-ranks -> E[] interval table.
//  - single ascending sweep per wave emits finished rows inline: sufP
//    subtractive from wave suffix seed (safe: wp monotone increasing in
//    sorted order), preN additive (exact prefix).
__global__ __launch_bounds__(512, 2) void k2_fused(
    const float* __restrict__ att, float* __restrict__ io) {
  __shared__ float tv[NA]; __shared__ int tpm[NA];
  __shared__ float sv[NA]; __shared__ int spm[NA];
  __shared__ float wp[NA]; __shared__ float wn[NA];
  __shared__ float rawP8[NW * 64]; __shared__ float rawN8[NW * 64];
  __shared__ float sufPc[(NW + 1) * 64]; __shared__ float preNc[(NW + 1) * 64];
  __shared__ float zps[NA + 1]; __shared__ float znp[NA + 1];
  __shared__ float szP[NC]; __shared__ float szN[NC];
  __shared__ float sufZ[NC + 1]; __shared__ float preZ[NC + 1];
  __shared__ float4 abi[NA];   // {A, B, 1/den, orig_row} per s-rank
  __shared__ int jsr[NA];      // js per s-rank (non-increasing)
  __shared__ int Earr[NA];     // E[j] = first rank with js <= j
  __shared__ float asrc[HD]; __shared__ float adst[HD];

  int bh = blockIdx.x;
  int head = bh & (NH - 1);
  int t = threadIdx.x;
  int lane = t & 63, w = t >> 6;
  float* vbase = io + (size_t)bh * NA * HD;

  if (t < 2 * HD) {
    float a = att[head * 2 * HD + t];
    if (t < HD) asrc[t] = a; else adst[t - HD] = a;
  }
  __syncthreads();

  // ---- s,t row-dots: thread t = natural row t (float4 loads, L3-hot) ----
  float vt, vs; int it = t, is_ = t;
  {
    const float4* vr = (const float4*)(vbase + (size_t)t * HD);
    float s0 = 0.f, s1 = 0.f, t0 = 0.f, t1 = 0.f;
    #pragma unroll
    for (int j = 0; j < HD / 4; j += 2) {
      float4 v0 = vr[j], v1 = vr[j + 1];
      s0 += v0.x*asrc[4*j+0] + v0.y*asrc[4*j+1] + v0.z*asrc[4*j+2] + v0.w*asrc[4*j+3];
      t0 += v0.x*adst[4*j+0] + v0.y*adst[4*j+1] + v0.z*adst[4*j+2] + v0.w*adst[4*j+3];
      s1 += v1.x*asrc[4*j+4] + v1.y*asrc[4*j+5] + v1.z*asrc[4*j+6] + v1.w*asrc[4*j+7];
      t1 += v1.x*adst[4*j+4] + v1.y*adst[4*j+5] + v1.z*adst[4*j+6] + v1.w*adst[4*j+7];
    }
    vs = s0 + s1; vt = t0 + t1;
  }

  // ---- dual hybrid bitonic sort (t asc, s asc), value+index in regs ----
  for (int size = 2; size <= NA; size <<= 1) {
    bool dirAsc = ((t & size) == 0);
    for (int stride = size >> 1; stride > 0; stride >>= 1) {
      float pt, ps; int pit, pis;
      if (stride >= 64) {
        tv[t] = vt; tpm[t] = it; sv[t] = vs; spm[t] = is_;
        __syncthreads();
        pt = tv[t ^ stride]; pit = tpm[t ^ stride];
        ps = sv[t ^ stride]; pis = spm[t ^ stride];
        __syncthreads();
      } else {
        pt = __shfl_xor(vt, stride, 64); pit = __shfl_xor(it, stride, 64);
        ps = __shfl_xor(vs, stride, 64); pis = __shfl_xor(is_, stride, 64);
      }
      bool mn = (((t & stride) == 0) == dirAsc);
      if (mn ? (pt < vt) : (pt > vt)) { vt = pt; it = pit; }
      if (mn ? (ps < vs) : (ps > vs)) { vs = ps; is_ = pis; }
    }
  }
  tv[t] = vt; tpm[t] = it; sv[t] = vs; spm[t] = is_;
  __syncthreads();

  float cmax = fmaxf(tv[NA - 1], 0.f);
  float amax = fmaxf(sv[NA - 1], 0.f);
  wp[t] = __expf(vt - cmax);
  wn[t] = __expf(NEG * vt - cmax);
  __syncthreads();

  // ---- phase A: V rows -> registers, wave-local weighted sums ----
  float vreg[64];
  {
    float aP = 0.f, aN = 0.f;
    #pragma unroll
    for (int jj = 0; jj < 64; ++jj) {
      int j = (w << 6) + jj;
      float vv = vbase[(size_t)tpm[j] * HD + lane];
      vreg[jj] = vv;
      aP += wp[j] * vv;
      aN += wn[j] * vv;
    }
    rawP8[(w << 6) + lane] = aP;
    rawN8[(w << 6) + lane] = aN;
  }
  __syncthreads();

  // ---- cross-wave scans (vector, G=64) + scalar chunk sums (G=16) ----
  if (t < 64) {
    int d = t; float run = 0.f;
    sufPc[NW * 64 + d] = 0.f;
    for (int ww = NW - 1; ww >= 0; --ww) {
      run += rawP8[ww * 64 + d]; sufPc[ww * 64 + d] = run;
    }
  } else if (t < 128) {
    int d = t - 64; float run = 0.f;
    for (int ww = 0; ww <= NW; ++ww) {
      preNc[ww * 64 + d] = run;
      if (ww < NW) run += rawN8[ww * 64 + d];
    }
  } else if (t < 160) {
    int c = t - 128; float a = 0.f;
    for (int j = c * CH; j < c * CH + CH; ++j) a += wp[j];
    szP[c] = a;
  } else if (t < 192) {
    int c = t - 160; float a = 0.f;
    for (int j = c * CH; j < c * CH + CH; ++j) a += wn[j];
    szN[c] = a;
  }
  __syncthreads();

  if (t == 0) {
    float run = 0.f; sufZ[NC] = 0.f;
    for (int cc = NC - 1; cc >= 0; --cc) { run += szP[cc]; sufZ[cc] = run; }
  } else if (t == 1) {
    float run = 0.f;
    for (int cc = 0; cc <= NC; ++cc) { preZ[cc] = run; if (cc < NC) run += szN[cc]; }
  }
  __syncthreads();

  // ---- full-resolution scalar denominator tables ----
  {
    int ch = t >> 4;
    float a = 0.f;
    for (int k = t; k < ch * CH + CH; ++k) a += wp[k];
    zps[t] = a + sufZ[ch + 1];
    float b2 = 0.f;
    for (int k = ch * CH; k < t; ++k) b2 += wn[k];
    znp[t] = preZ[ch] + b2;
    if (t == 0) { zps[NA] = 0.f; znp[NA] = preZ[NC]; }
  }
  __syncthreads();

  // ---- per-rank info: thread t = s-rank t (holds vs, is_ in regs) ----
  {
    float A = __expf(vs - amax);
    float B = __expf(NEG * vs - amax);
    float key = -vs;
    int lo = 0, hi = NA;
    while (lo < hi) { int mid = (lo + hi) >> 1; if (tv[mid] < key) lo = mid + 1; else hi = mid; }
    float den = A * zps[lo] + B * znp[lo];
    float4 q; q.x = A; q.y = B; q.z = 1.f / den; q.w = __int_as_float(is_);
    abi[t] = q;
    jsr[t] = lo;
  }
  __syncthreads();

  // ---- E[j]: first rank with jsr <= j (jsr sorted descending) ----
  {
    int lo = 0, hi = NA;
    while (lo < hi) { int mid = (lo + hi) >> 1; if (jsr[mid] > t) lo = mid + 1; else hi = mid; }
    Earr[t] = lo;
  }
  __syncthreads();

  // ---- single ascending sweep with inline emission (writes io in place) ----
  {
    float sufPv = sufPc[w * 64 + lane];      // suffix incl. this wave's rows
    float preSeedN = preNc[w * 64 + lane];   // exact prefix before this wave
    float runN = 0.f;
    size_t obase = (size_t)bh * NA * HD + lane;
    int eprev = (w == 0) ? NA : Earr[(w << 6) - 1];   // E[j-1] carried
    #pragma unroll
    for (int jj = 0; jj < 64; ++jj) {
      int j = (w << 6) + jj;
      int ecur = Earr[j];
      float preNv = preSeedN + runN;
      for (int r = ecur; r < eprev; ++r) {   // ranks with js == j
        float4 q = abi[r];
        float x = (q.x * sufPv + q.y * preNv) * q.z;
        int orow = __float_as_int(q.w);
        io[obase + (size_t)orow * HD] = x > 0.f ? x : __expf(x) - 1.f;
      }
      float vv = vreg[jj];
      sufPv -= wp[j] * vv;
      runN  += wn[j] * vv;
      eprev = ecur;
    }
    if (w == NW - 1) {                       // group js == 512: [0, E[511])
      float preNv = preSeedN + runN;         // == total N prefix
      for (int r = 0; r < eprev; ++r) {
        float4 q = abi[r];
        float x = (q.y * preNv) * q.z;       // sufP[512] == 0
        int orow = __float_as_int(q.w);
        io[obase + (size_t)orow * HD] = x > 0.f ? x : __expf(x) - 1.f;
      }
    }
  }
}

extern "C" void kernel_launch(void* const* d_in, const int* in_sizes, int n_in,
                              void* d_out, int out_size, void* d_ws, size_t ws_size,
                              hipStream_t stream) {
  const float* h   = (const float*)d_in[0];
  const float* W   = (const float*)d_in[1];
  const float* att = (const float*)d_in[2];
  float* io = (float*)d_out;
  (void)d_ws; (void)ws_size;

  k1_gemm <<<dim3(1024),    dim3(256), 0, stream>>>(h, W, io);
  k2_fused<<<dim3(BS * NH), dim3(512), 0, stream>>>(att, io);
}

// Round 4
// 126.139 us; speedup vs baseline: 1.2478x; 1.0693x over previous
//
#include <hip/hip_runtime.h>

#define BS 32
#define NA 512
#define ID 128
#define NH 8
#define HD 64
#define NHD 512   // NH*HD
#define NEG 0.2f
#define NC 32     // scalar chunk count (G=16) for zps/znp
#define CH 16
#define NW 8      // waves per k2 block (512 threads)
#define BPAD 136  // B LDS col stride (bf16 elems): 272B -> 2-way bank alias (free)

typedef short bf16x8 __attribute__((ext_vector_type(8)));
typedef float f32x4 __attribute__((ext_vector_type(4)));

__device__ inline unsigned f2bf_bits(float x) {   // RNE f32 -> bf16 bits
  unsigned u = __float_as_uint(x);
  return (u + 0x7FFFu + ((u >> 16) & 1u)) >> 16;
}

// split 8 floats into bf16 hi + bf16 lo fragments (static indices only)
__device__ inline void split8(const float4& x, const float4& y,
                              bf16x8& hi, bf16x8& lo) {
  float f[8] = {x.x, x.y, x.z, x.w, y.x, y.y, y.z, y.w};
  #pragma unroll
  for (int j = 0; j < 8; ++j) {
    unsigned hb = f2bf_bits(f[j]);
    float r = f[j] - __uint_as_float(hb << 16);
    unsigned lb = f2bf_bits(r);
    hi[j] = (short)hb;
    lo[j] = (short)lb;
  }
}

// K1 (MFMA): hp = h @ W via split-bf16 3-pass (hi*hi + hi*lo + lo*hi), fp32
// accumulate. Error ~2^-16 relative (negligible vs fp32 path). Block = 128
// M-rows x 64 N-cols, 256 threads (4 waves x 32 rows). W slice is split +
// transposed into padded LDS ([col][k], stride 136 bf16 = 2-way bank alias);
// h is split inline from fp32. A/B fragments are packed with the SAME
// (quarter,elem)->k mapping on both sides, so the hardware k-permutation
// cancels; only the C/D layout (col=lane&15, row=4*(lane>>4)+reg, HW-verified)
// matters. Writes straight into io (d_out).
__global__ __launch_bounds__(256, 4) void k1_mfma(
    const float* __restrict__ h, const float* __restrict__ W,
    float* __restrict__ io) {
  __shared__ unsigned short Bhi[64 * BPAD];
  __shared__ unsigned short Blo[64 * BPAD];

  int blk = blockIdx.x;
  int mt = blk >> 3;            // M-tile 0..127 (128 rows each)
  int n0 = (blk & 7) * 64;      // N-tile start col
  int m0 = mt * 128;
  int b = mt >> 2;              // batch
  int nbase = (mt & 3) * 128;   // agent-row base within batch
  int head = n0 >> 6;
  int t = threadIdx.x;
  int lane = t & 63, w = t >> 6;
  int q = lane >> 4, ml = lane & 15;

  // ---- stage W[n0..n0+63] split+transposed into LDS ----
  {
    int c = t & 63, kq = t >> 6;
    const float* wsrc = W + (size_t)kq * 32 * NHD + n0 + c;
    #pragma unroll 4
    for (int kk = 0; kk < 32; ++kk) {
      int k = kq * 32 + kk;
      float x = wsrc[(size_t)kk * NHD];
      unsigned hb = f2bf_bits(x);
      float r = x - __uint_as_float(hb << 16);
      Bhi[c * BPAD + k] = (unsigned short)hb;
      Blo[c * BPAD + k] = (unsigned short)f2bf_bits(r);
    }
  }
  __syncthreads();

  f32x4 acc[2][4];
  #pragma unroll
  for (int mf = 0; mf < 2; ++mf)
    #pragma unroll
    for (int nf = 0; nf < 4; ++nf)
      acc[mf][nf] = (f32x4){0.f, 0.f, 0.f, 0.f};

  const float* A0 = h + (size_t)(m0 + w * 32 + ml) * ID;

  #pragma unroll
  for (int ks = 0; ks < 4; ++ks) {
    int ko = ks * 32 + q * 8;          // my k mapping: k = 8*quarter + elem
    bf16x8 ah[2], al[2];
    #pragma unroll
    for (int mf = 0; mf < 2; ++mf) {
      const float* ap = A0 + mf * 16 * ID + ko;
      float4 f0 = *(const float4*)ap;
      float4 f1 = *(const float4*)(ap + 4);
      split8(f0, f1, ah[mf], al[mf]);
    }
    #pragma unroll
    for (int nf = 0; nf < 4; ++nf) {
      int bo = (nf * 16 + ml) * BPAD + ko;   // same k mapping on B side
      bf16x8 bh = *(const bf16x8*)&Bhi[bo];
      bf16x8 bl = *(const bf16x8*)&Blo[bo];
      #pragma unroll
      for (int mf = 0; mf < 2; ++mf) {
        acc[mf][nf] = __builtin_amdgcn_mfma_f32_16x16x32_bf16(ah[mf], bh, acc[mf][nf], 0, 0, 0);
        acc[mf][nf] = __builtin_amdgcn_mfma_f32_16x16x32_bf16(ah[mf], bl, acc[mf][nf], 0, 0, 0);
        acc[mf][nf] = __builtin_amdgcn_mfma_f32_16x16x32_bf16(al[mf], bh, acc[mf][nf], 0, 0, 0);
      }
    }
  }

  // ---- epilogue: D layout col=lane&15, row=4*(lane>>4)+reg (HW-verified) ----
  {
    float* ob = io + (((size_t)b * NH + head) * NA + nbase + w * 32) * HD + ml;
    #pragma unroll
    for (int mf = 0; mf < 2; ++mf)
      #pragma unroll
      for (int nf = 0; nf < 4; ++nf)
        #pragma unroll
        for (int r = 0; r < 4; ++r)
          ob[(size_t)(mf * 16 + q * 4 + r) * HD + nf * 16] = acc[mf][nf][r];
  }
}

// K2 (in-place): per (b,h) block of 512 threads. io holds hp on entry, final
// output on exit. Unchanged from R3 (verified).
__global__ __launch_bounds__(512, 2) void k2_fused(
    const float* __restrict__ att, float* __restrict__ io) {
  __shared__ float tv[NA]; __shared__ int tpm[NA];
  __shared__ float sv[NA]; __shared__ int spm[NA];
  __shared__ float wp[NA]; __shared__ float wn[NA];
  __shared__ float rawP8[NW * 64]; __shared__ float rawN8[NW * 64];
  __shared__ float sufPc[(NW + 1) * 64]; __shared__ float preNc[(NW + 1) * 64];
  __shared__ float zps[NA + 1]; __shared__ float znp[NA + 1];
  __shared__ float szP[NC]; __shared__ float szN[NC];
  __shared__ float sufZ[NC + 1]; __shared__ float preZ[NC + 1];
  __shared__ float4 abi[NA];   // {A, B, 1/den, orig_row} per s-rank
  __shared__ int jsr[NA];      // js per s-rank (non-increasing)
  __shared__ int Earr[NA];     // E[j] = first rank with js <= j
  __shared__ float asrc[HD]; __shared__ float adst[HD];

  int bh = blockIdx.x;
  int head = bh & (NH - 1);
  int t = threadIdx.x;
  int lane = t & 63, w = t >> 6;
  float* vbase = io + (size_t)bh * NA * HD;

  if (t < 2 * HD) {
    float a = att[head * 2 * HD + t];
    if (t < HD) asrc[t] = a; else adst[t - HD] = a;
  }
  __syncthreads();

  // ---- s,t row-dots: thread t = natural row t (float4 loads, L3-hot) ----
  float vt, vs; int it = t, is_ = t;
  {
    const float4* vr = (const float4*)(vbase + (size_t)t * HD);
    float s0 = 0.f, s1 = 0.f, t0 = 0.f, t1 = 0.f;
    #pragma unroll
    for (int j = 0; j < HD / 4; j += 2) {
      float4 v0 = vr[j], v1 = vr[j + 1];
      s0 += v0.x*asrc[4*j+0] + v0.y*asrc[4*j+1] + v0.z*asrc[4*j+2] + v0.w*asrc[4*j+3];
      t0 += v0.x*adst[4*j+0] + v0.y*adst[4*j+1] + v0.z*adst[4*j+2] + v0.w*adst[4*j+3];
      s1 += v1.x*asrc[4*j+4] + v1.y*asrc[4*j+5] + v1.z*asrc[4*j+6] + v1.w*asrc[4*j+7];
      t1 += v1.x*adst[4*j+4] + v1.y*adst[4*j+5] + v1.z*adst[4*j+6] + v1.w*adst[4*j+7];
    }
    vs = s0 + s1; vt = t0 + t1;
  }

  // ---- dual hybrid bitonic sort (t asc, s asc), value+index in regs ----
  for (int size = 2; size <= NA; size <<= 1) {
    bool dirAsc = ((t & size) == 0);
    for (int stride = size >> 1; stride > 0; stride >>= 1) {
      float pt, ps; int pit, pis;
      if (stride >= 64) {
        tv[t] = vt; tpm[t] = it; sv[t] = vs; spm[t] = is_;
        __syncthreads();
        pt = tv[t ^ stride]; pit = tpm[t ^ stride];
        ps = sv[t ^ stride]; pis = spm[t ^ stride];
        __syncthreads();
      } else {
        pt = __shfl_xor(vt, stride, 64); pit = __shfl_xor(it, stride, 64);
        ps = __shfl_xor(vs, stride, 64); pis = __shfl_xor(is_, stride, 64);
      }
      bool mn = (((t & stride) == 0) == dirAsc);
      if (mn ? (pt < vt) : (pt > vt)) { vt = pt; it = pit; }
      if (mn ? (ps < vs) : (ps > vs)) { vs = ps; is_ = pis; }
    }
  }
  tv[t] = vt; tpm[t] = it; sv[t] = vs; spm[t] = is_;
  __syncthreads();

  float cmax = fmaxf(tv[NA - 1], 0.f);
  float amax = fmaxf(sv[NA - 1], 0.f);
  wp[t] = __expf(vt - cmax);
  wn[t] = __expf(NEG * vt - cmax);
  __syncthreads();

  // ---- phase A: V rows -> registers, wave-local weighted sums ----
  float vreg[64];
  {
    float aP = 0.f, aN = 0.f;
    #pragma unroll
    for (int jj = 0; jj < 64; ++jj) {
      int j = (w << 6) + jj;
      float vv = vbase[(size_t)tpm[j] * HD + lane];
      vreg[jj] = vv;
      aP += wp[j] * vv;
      aN += wn[j] * vv;
    }
    rawP8[(w << 6) + lane] = aP;
    rawN8[(w << 6) + lane] = aN;
  }
  __syncthreads();

  // ---- cross-wave scans (vector, G=64) + scalar chunk sums (G=16) ----
  if (t < 64) {
    int d = t; float run = 0.f;
    sufPc[NW * 64 + d] = 0.f;
    for (int ww = NW - 1; ww >= 0; --ww) {
      run += rawP8[ww * 64 + d]; sufPc[ww * 64 + d] = run;
    }
  } else if (t < 128) {
    int d = t - 64; float run = 0.f;
    for (int ww = 0; ww <= NW; ++ww) {
      preNc[ww * 64 + d] = run;
      if (ww < NW) run += rawN8[ww * 64 + d];
    }
  } else if (t < 160) {
    int c = t - 128; float a = 0.f;
    for (int j = c * CH; j < c * CH + CH; ++j) a += wp[j];
    szP[c] = a;
  } else if (t < 192) {
    int c = t - 160; float a = 0.f;
    for (int j = c * CH; j < c * CH + CH; ++j) a += wn[j];
    szN[c] = a;
  }
  __syncthreads();

  if (t == 0) {
    float run = 0.f; sufZ[NC] = 0.f;
    for (int cc = NC - 1; cc >= 0; --cc) { run += szP[cc]; sufZ[cc] = run; }
  } else if (t == 1) {
    float run = 0.f;
    for (int cc = 0; cc <= NC; ++cc) { preZ[cc] = run; if (cc < NC) run += szN[cc]; }
  }
  __syncthreads();

  // ---- full-resolution scalar denominator tables ----
  {
    int ch = t >> 4;
    float a = 0.f;
    for (int k = t; k < ch * CH + CH; ++k) a += wp[k];
    zps[t] = a + sufZ[ch + 1];
    float b2 = 0.f;
    for (int k = ch * CH; k < t; ++k) b2 += wn[k];
    znp[t] = preZ[ch] + b2;
    if (t == 0) { zps[NA] = 0.f; znp[NA] = preZ[NC]; }
  }
  __syncthreads();

  // ---- per-rank info: thread t = s-rank t (holds vs, is_ in regs) ----
  {
    float A = __expf(vs - amax);
    float B = __expf(NEG * vs - amax);
    float key = -vs;
    int lo = 0, hi = NA;
    while (lo < hi) { int mid = (lo + hi) >> 1; if (tv[mid] < key) lo = mid + 1; else hi = mid; }
    float den = A * zps[lo] + B * znp[lo];
    float4 qv; qv.x = A; qv.y = B; qv.z = 1.f / den; qv.w = __int_as_float(is_);
    abi[t] = qv;
    jsr[t] = lo;
  }
  __syncthreads();

  // ---- E[j]: first rank with jsr <= j (jsr sorted descending) ----
  {
    int lo = 0, hi = NA;
    while (lo < hi) { int mid = (lo + hi) >> 1; if (jsr[mid] > t) lo = mid + 1; else hi = mid; }
    Earr[t] = lo;
  }
  __syncthreads();

  // ---- single ascending sweep with inline emission (writes io in place) ----
  {
    float sufPv = sufPc[w * 64 + lane];      // suffix incl. this wave's rows
    float preSeedN = preNc[w * 64 + lane];   // exact prefix before this wave
    float runN = 0.f;
    size_t obase = (size_t)bh * NA * HD + lane;
    int eprev = (w == 0) ? NA : Earr[(w << 6) - 1];   // E[j-1] carried
    #pragma unroll
    for (int jj = 0; jj < 64; ++jj) {
      int j = (w << 6) + jj;
      int ecur = Earr[j];
      float preNv = preSeedN + runN;
      for (int r = ecur; r < eprev; ++r) {   // ranks with js == j
        float4 qv = abi[r];
        float x = (qv.x * sufPv + qv.y * preNv) * qv.z;
        int orow = __float_as_int(qv.w);
        io[obase + (size_t)orow * HD] = x > 0.f ? x : __expf(x) - 1.f;
      }
      float vv = vreg[jj];
      sufPv -= wp[j] * vv;
      runN  += wn[j] * vv;
      eprev = ecur;
    }
    if (w == NW - 1) {                       // group js == 512: [0, E[511])
      float preNv = preSeedN + runN;         // == total N prefix
      for (int r = 0; r < eprev; ++r) {
        float4 qv = abi[r];
        float x = (qv.y * preNv) * qv.z;     // sufP[512] == 0
        int orow = __float_as_int(qv.w);
        io[obase + (size_t)orow * HD] = x > 0.f ? x : __expf(x) - 1.f;
      }
    }
  }
}

extern "C" void kernel_launch(void* const* d_in, const int* in_sizes, int n_in,
                              void* d_out, int out_size, void* d_ws, size_t ws_size,
                              hipStream_t stream) {
  const float* h   = (const float*)d_in[0];
  const float* W   = (const float*)d_in[1];
  const float* att = (const float*)d_in[2];
  float* io = (float*)d_out;
  (void)d_ws; (void)ws_size;

  k1_mfma <<<dim3(1024),    dim3(256), 0, stream>>>(h, W, io);
  k2_fused<<<dim3(BS * NH), dim3(512), 0, stream>>>(att, io);
}